// Round 1
// baseline (3042.881 us; speedup 1.0000x reference)
//
#include <hip/hip_runtime.h>
#include <math.h>

// Problem constants: x [8,64,64,64] fp32 NCHW, W_std [64,64,3,3] fp32 OIHW.
#define BB 8
#define CC 64
#define HH 64
#define WW 64
#define NPIX (HH*WW)   // 4096

// ---------------------------------------------------------------------------
// Conv: feat = conv3x3(x, W_std) + depthwise Laplacian(x).
// Writes TRANSPOSED layout featT[b][n=y*64+x][c] so attention Q/K rows are
// contiguous 256B.
// grid (16 ytiles, 64 o, 8 b), block 256 = 64x * 4y. One output per thread.
// W reads are wave-uniform (o, c uniform) -> scalar loads.
// ---------------------------------------------------------------------------
__global__ __launch_bounds__(256) void conv_kernel(
    const float* __restrict__ xin, const float* __restrict__ w,
    float* __restrict__ featT) {
  const int xc = threadIdx.x & 63;
  const int yl = threadIdx.x >> 6;
  const int o  = blockIdx.y;
  const int b  = blockIdx.z;
  const int y  = blockIdx.x * 4 + yl;

  const float* xb = xin + (size_t)b * CC * NPIX;
  const float* wo = w + o * (CC * 9);

  float acc = 0.f;
  for (int c = 0; c < CC; ++c) {
    const float* wc = wo + c * 9;
    const float w0 = wc[0], w1 = wc[1], w2 = wc[2];
    const float w3 = wc[3], w4 = wc[4], w5 = wc[5];
    const float w6 = wc[6], w7 = wc[7], w8 = wc[8];
    const float* xcn = xb + c * NPIX;
    float v[3][3];
#pragma unroll
    for (int ky = 0; ky < 3; ++ky) {
      const int yy = y + ky - 1;
      const bool yok = (yy >= 0) && (yy < HH);
      const float* row = xcn + yy * WW;
#pragma unroll
      for (int kx = 0; kx < 3; ++kx) {
        const int xx = xc + kx - 1;
        const bool ok = yok && (xx >= 0) && (xx < WW);
        v[ky][kx] = ok ? row[xx] : 0.f;
      }
    }
    acc += w0*v[0][0] + w1*v[0][1] + w2*v[0][2]
         + w3*v[1][0] + w4*v[1][1] + w5*v[1][2]
         + w6*v[2][0] + w7*v[2][1] + w8*v[2][2];
    if (c == o) {  // fixed depthwise Laplacian on matching channel
      acc += v[0][1] + v[2][1] + v[1][0] + v[1][2] - 4.f*v[1][1];
    }
  }
  featT[((size_t)b * NPIX + y * WW + xc) * CC + o] = acc;
}

// ---------------------------------------------------------------------------
// 2x2 average pool on transposed layout. Exact divisor (power of 2).
// pool4 is computed as pool2(pool2(feat)) - numerically equivalent.
// ---------------------------------------------------------------------------
__global__ void pool2_kernel(const float* __restrict__ in,
                             float* __restrict__ out, int hw_out) {
  // in:  [B][ (2h)*(2w) ][64], out: [B][ h*w ][64]; hw_out = h (==w)
  const int idx = blockIdx.x * blockDim.x + threadIdx.x;
  const int c  = idx & 63;
  const int t  = idx >> 6;
  const int xo = t % hw_out;
  const int r  = t / hw_out;
  const int yo = r % hw_out;
  const int b  = r / hw_out;
  const int win = 2 * hw_out;
  const float* base = in + ((size_t)b * win * win) * 64;
  float s = 0.f;
#pragma unroll
  for (int dy = 0; dy < 2; ++dy)
#pragma unroll
    for (int dx = 0; dx < 2; ++dx)
      s += base[((2*yo+dy) * win + (2*xo+dx)) * 64 + c];
  out[idx] = 0.25f * s;
}

// ---------------------------------------------------------------------------
// Non-local attention, flash-style online softmax. One thread per query.
// fT: [B][N][64]. K-row addresses are wave-uniform -> scalar loads; the
// inner loop is 128 v_fma per (q,m).
// grid (N/256, B), block 256.
// ---------------------------------------------------------------------------
__global__ __launch_bounds__(256) void attn_kernel(
    const float* __restrict__ fT, float* __restrict__ outT, int N) {
  const int q = blockIdx.x * 256 + threadIdx.x;
  const int b = blockIdx.y;
  const float* fb = fT + (size_t)b * N * 64;

  float4 Q[16];
  const float4* qrow = (const float4*)(fb + (size_t)q * 64);
#pragma unroll
  for (int i = 0; i < 16; ++i) Q[i] = qrow[i];

  float acc[64];
#pragma unroll
  for (int i = 0; i < 64; ++i) acc[i] = 0.f;
  float mrun = -INFINITY;
  float l = 0.f;

  for (int m = 0; m < N; ++m) {
    const float4* krow = (const float4*)(fb + (size_t)m * 64);
    float4 K[16];
#pragma unroll
    for (int i = 0; i < 16; ++i) K[i] = krow[i];

    float s = 0.f;
#pragma unroll
    for (int i = 0; i < 16; ++i)
      s += Q[i].x*K[i].x + Q[i].y*K[i].y + Q[i].z*K[i].z + Q[i].w*K[i].w;

    if (s > mrun) {                 // rare after warm-up: running-max update
      const float f = __expf(mrun - s);   // first iter: exp(-inf)=0
      l *= f;
#pragma unroll
      for (int i = 0; i < 64; ++i) acc[i] *= f;
      mrun = s;
    }
    const float p = __expf(s - mrun);
    l += p;
#pragma unroll
    for (int i = 0; i < 16; ++i) {
      acc[4*i+0] += p * K[i].x;
      acc[4*i+1] += p * K[i].y;
      acc[4*i+2] += p * K[i].z;
      acc[4*i+3] += p * K[i].w;
    }
  }

  const float inv = 1.f / l;
  float4* orow = (float4*)(outT + ((size_t)b * N + q) * 64);
#pragma unroll
  for (int i = 0; i < 16; ++i)
    orow[i] = make_float4(acc[4*i]*inv, acc[4*i+1]*inv,
                          acc[4*i+2]*inv, acc[4*i+3]*inv);
}

// ---------------------------------------------------------------------------
// out[b][c][y][x] = x + a1[b][n][c] + bilinear_up2(a2) + bilinear_up4(a4)
// Half-pixel centers; at most one tap OOB -> clamping == jax renormalization.
// grid (16 ytiles, 64 c, 8 b), block 256 = 64x * 4y.
// ---------------------------------------------------------------------------
__global__ __launch_bounds__(256) void final_kernel(
    const float* __restrict__ xin, const float* __restrict__ a1,
    const float* __restrict__ a2, const float* __restrict__ a4,
    float* __restrict__ out) {
  const int xc = threadIdx.x & 63;
  const int yl = threadIdx.x >> 6;
  const int y  = blockIdx.x * 4 + yl;
  const int c  = blockIdx.y;
  const int b  = blockIdx.z;

  float r = xin[(((size_t)b * CC + c) * HH + y) * WW + xc];
  r += a1[((size_t)b * NPIX + y * WW + xc) * CC + c];

  {  // scale 2: 32x32 source. src = (y+0.5)/2 - 0.5 = y/2 - 0.25
    const float ty = y * 0.5f - 0.25f;
    const float tx = xc * 0.5f - 0.25f;
    const int iy = (int)floorf(ty), ix = (int)floorf(tx);
    const float wy = ty - iy, wx = tx - ix;
    const int iy0 = max(iy, 0), iy1 = min(iy + 1, 31);
    const int ix0 = max(ix, 0), ix1 = min(ix + 1, 31);
    const float* base = a2 + (size_t)b * 1024 * 64 + c;
    const float v00 = base[(iy0*32+ix0)*64], v01 = base[(iy0*32+ix1)*64];
    const float v10 = base[(iy1*32+ix0)*64], v11 = base[(iy1*32+ix1)*64];
    r += (1.f-wy)*((1.f-wx)*v00 + wx*v01) + wy*((1.f-wx)*v10 + wx*v11);
  }
  {  // scale 4: 16x16 source. src = (y+0.5)/4 - 0.5 = y/4 - 0.375
    const float ty = y * 0.25f - 0.375f;
    const float tx = xc * 0.25f - 0.375f;
    const int iy = (int)floorf(ty), ix = (int)floorf(tx);
    const float wy = ty - iy, wx = tx - ix;
    const int iy0 = max(iy, 0), iy1 = min(iy + 1, 15);
    const int ix0 = max(ix, 0), ix1 = min(ix + 1, 15);
    const float* base = a4 + (size_t)b * 256 * 64 + c;
    const float v00 = base[(iy0*16+ix0)*64], v01 = base[(iy0*16+ix1)*64];
    const float v10 = base[(iy1*16+ix0)*64], v11 = base[(iy1*16+ix1)*64];
    r += (1.f-wy)*((1.f-wx)*v00 + wx*v01) + wy*((1.f-wx)*v10 + wx*v11);
  }
  out[(((size_t)b * CC + c) * HH + y) * WW + xc] = r;
}

// ---------------------------------------------------------------------------
extern "C" void kernel_launch(void* const* d_in, const int* in_sizes, int n_in,
                              void* d_out, int out_size, void* d_ws,
                              size_t ws_size, hipStream_t stream) {
  const float* x = (const float*)d_in[0];
  const float* w = (const float*)d_in[1];
  float* out = (float*)d_out;

  float* featT = (float*)d_ws;                  // 8*4096*64
  float* p2    = featT + (size_t)BB*NPIX*CC;    // 8*1024*64
  float* p4    = p2    + (size_t)BB*1024*CC;    // 8*256*64
  float* a1    = p4    + (size_t)BB*256*CC;     // 8*4096*64
  float* a2    = a1    + (size_t)BB*NPIX*CC;    // 8*1024*64
  float* a4    = a2    + (size_t)BB*1024*CC;    // 8*256*64

  conv_kernel<<<dim3(16, 64, 8), 256, 0, stream>>>(x, w, featT);
  pool2_kernel<<<(BB*1024*CC)/256, 256, 0, stream>>>(featT, p2, 32);
  pool2_kernel<<<(BB*256*CC)/256, 256, 0, stream>>>(p2, p4, 16);
  attn_kernel<<<dim3(NPIX/256, BB), 256, 0, stream>>>(featT, a1, NPIX);
  attn_kernel<<<dim3(1024/256, BB), 256, 0, stream>>>(p2, a2, 1024);
  attn_kernel<<<dim3(256/256, BB), 256, 0, stream>>>(p4, a4, 256);
  final_kernel<<<dim3(16, 64, 8), 256, 0, stream>>>(x, a1, a2, a4, out);
}

// Round 2
// 1341.438 us; speedup vs baseline: 2.2684x; 2.2684x over previous
//
#include <hip/hip_runtime.h>
#include <math.h>

// Problem constants: x [8,64,64,64] fp32 NCHW, W_std [64,64,3,3] fp32 OIHW.
#define BB 8
#define CC 64
#define HH 64
#define WW 64
#define NPIX (HH*WW)   // 4096

// ---------------------------------------------------------------------------
// Conv: feat = conv3x3(x, W_std) + depthwise Laplacian(x).
// Writes TRANSPOSED layout featT[b][n=y*64+x][c] so attention Q/K rows are
// contiguous 256B.
// grid (16 ytiles, 64 o, 8 b), block 256 = 64x * 4y. One output per thread.
// W reads are wave-uniform (o, c uniform) -> scalar loads.
// ---------------------------------------------------------------------------
__global__ __launch_bounds__(256) void conv_kernel(
    const float* __restrict__ xin, const float* __restrict__ w,
    float* __restrict__ featT) {
  const int xc = threadIdx.x & 63;
  const int yl = threadIdx.x >> 6;
  const int o  = blockIdx.y;
  const int b  = blockIdx.z;
  const int y  = blockIdx.x * 4 + yl;

  const float* xb = xin + (size_t)b * CC * NPIX;
  const float* wo = w + o * (CC * 9);

  float acc = 0.f;
  for (int c = 0; c < CC; ++c) {
    const float* wc = wo + c * 9;
    const float w0 = wc[0], w1 = wc[1], w2 = wc[2];
    const float w3 = wc[3], w4 = wc[4], w5 = wc[5];
    const float w6 = wc[6], w7 = wc[7], w8 = wc[8];
    const float* xcn = xb + c * NPIX;
    float v[3][3];
#pragma unroll
    for (int ky = 0; ky < 3; ++ky) {
      const int yy = y + ky - 1;
      const bool yok = (yy >= 0) && (yy < HH);
      const float* row = xcn + yy * WW;
#pragma unroll
      for (int kx = 0; kx < 3; ++kx) {
        const int xx = xc + kx - 1;
        const bool ok = yok && (xx >= 0) && (xx < WW);
        v[ky][kx] = ok ? row[xx] : 0.f;
      }
    }
    acc += w0*v[0][0] + w1*v[0][1] + w2*v[0][2]
         + w3*v[1][0] + w4*v[1][1] + w5*v[1][2]
         + w6*v[2][0] + w7*v[2][1] + w8*v[2][2];
    if (c == o) {  // fixed depthwise Laplacian on matching channel
      acc += v[0][1] + v[2][1] + v[1][0] + v[1][2] - 4.f*v[1][1];
    }
  }
  featT[((size_t)b * NPIX + y * WW + xc) * CC + o] = acc;
}

// ---------------------------------------------------------------------------
// 2x2 average pool on transposed layout. Exact divisor (power of 2).
// pool4 is computed as pool2(pool2(feat)) - numerically equivalent.
// ---------------------------------------------------------------------------
__global__ void pool2_kernel(const float* __restrict__ in,
                             float* __restrict__ out, int hw_out) {
  const int idx = blockIdx.x * blockDim.x + threadIdx.x;
  const int c  = idx & 63;
  const int t  = idx >> 6;
  const int xo = t % hw_out;
  const int r  = t / hw_out;
  const int yo = r % hw_out;
  const int b  = r / hw_out;
  const int win = 2 * hw_out;
  const float* base = in + ((size_t)b * win * win) * 64;
  float s = 0.f;
#pragma unroll
  for (int dy = 0; dy < 2; ++dy)
#pragma unroll
    for (int dx = 0; dx < 2; ++dx)
      s += base[((2*yo+dy) * win + (2*xo+dx)) * 64 + c];
  out[idx] = 0.25f * s;
}

// ---------------------------------------------------------------------------
// Non-local attention, flash-style online softmax with IN-BLOCK SPLIT-K.
// Block = 256 threads = 4 waves. lane (0..63) owns query q = blockX*64+lane;
// wave w covers keys [w*N/4, (w+1)*N/4). Partial (m, l, acc[64]) merged via
// LDS with log-sum-exp algebra; wave 0 writes the result.
//   - launch_bounds(256,2): VGPR cap 256 -> Q[64]+acc[64] live in registers
//     (round-1 spilled at the default cap: VGPR_Count was 72).
//   - grid (N/64, B): scale-1 -> 512 blocks = 2 blocks/CU, 8 waves/CU.
//   - dot uses 4 accumulators to break the 64-deep FMA dependence chain.
// ---------------------------------------------------------------------------
__global__ __launch_bounds__(256, 2) void attn_kernel(
    const float* __restrict__ fT, float* __restrict__ outT, int N) {
  __shared__ float mbuf[64][66];   // [lane][0..63]=acc, [64]=m, [65]=l

  const int lane = threadIdx.x & 63;
  const int wave = threadIdx.x >> 6;
  const int q = blockIdx.x * 64 + lane;
  const int b = blockIdx.y;
  const float* fb = fT + (size_t)b * N * 64;

  float4 Q[16];
  const float4* qrow = (const float4*)(fb + (size_t)q * 64);
#pragma unroll
  for (int i = 0; i < 16; ++i) Q[i] = qrow[i];

  float acc[64];
#pragma unroll
  for (int i = 0; i < 64; ++i) acc[i] = 0.f;
  float mrun = -INFINITY;
  float l = 0.f;

  const int chunk = N >> 2;            // N/4 keys per wave
  const float4* krow = (const float4*)(fb + (size_t)(wave * chunk) * 64);

  for (int m = 0; m < chunk; ++m, krow += 16) {
    float4 K[16];
#pragma unroll
    for (int i = 0; i < 16; ++i) K[i] = krow[i];

    float s0 = 0.f, s1 = 0.f, s2 = 0.f, s3 = 0.f;
#pragma unroll
    for (int i = 0; i < 16; ++i) {
      s0 += Q[i].x * K[i].x;
      s1 += Q[i].y * K[i].y;
      s2 += Q[i].z * K[i].z;
      s3 += Q[i].w * K[i].w;
    }
    const float s = (s0 + s1) + (s2 + s3);

    if (s > mrun) {                 // rare after warm-up
      const float f = __expf(mrun - s);   // first iter: exp(-inf)=0
      l *= f;
#pragma unroll
      for (int i = 0; i < 64; ++i) acc[i] *= f;
      mrun = s;
    }
    const float p = __expf(s - mrun);
    l += p;
#pragma unroll
    for (int i = 0; i < 16; ++i) {
      acc[4*i+0] += p * K[i].x;
      acc[4*i+1] += p * K[i].y;
      acc[4*i+2] += p * K[i].z;
      acc[4*i+3] += p * K[i].w;
    }
  }

  // ---- merge the 4 per-wave partials into wave 0 (3 sequential rounds) ----
  for (int s = 1; s < 4; ++s) {
    __syncthreads();
    if (wave == s) {
#pragma unroll
      for (int i = 0; i < 64; ++i) mbuf[lane][i] = acc[i];
      mbuf[lane][64] = mrun;
      mbuf[lane][65] = l;
    }
    __syncthreads();
    if (wave == 0) {
      const float ms = mbuf[lane][64];
      const float ls = mbuf[lane][65];
      const float M  = fmaxf(mrun, ms);
      const float e0 = __expf(mrun - M);
      const float es = __expf(ms - M);
#pragma unroll
      for (int i = 0; i < 64; ++i)
        acc[i] = acc[i] * e0 + mbuf[lane][i] * es;
      l = l * e0 + ls * es;
      mrun = M;
    }
  }

  if (wave == 0) {
    const float inv = 1.f / l;
    float4* orow = (float4*)(outT + ((size_t)b * N + q) * 64);
#pragma unroll
    for (int i = 0; i < 16; ++i)
      orow[i] = make_float4(acc[4*i]*inv, acc[4*i+1]*inv,
                            acc[4*i+2]*inv, acc[4*i+3]*inv);
  }
}

// ---------------------------------------------------------------------------
// out[b][c][y][x] = x + a1[b][n][c] + bilinear_up2(a2) + bilinear_up4(a4)
// ---------------------------------------------------------------------------
__global__ __launch_bounds__(256) void final_kernel(
    const float* __restrict__ xin, const float* __restrict__ a1,
    const float* __restrict__ a2, const float* __restrict__ a4,
    float* __restrict__ out) {
  const int xc = threadIdx.x & 63;
  const int yl = threadIdx.x >> 6;
  const int y  = blockIdx.x * 4 + yl;
  const int c  = blockIdx.y;
  const int b  = blockIdx.z;

  float r = xin[(((size_t)b * CC + c) * HH + y) * WW + xc];
  r += a1[((size_t)b * NPIX + y * WW + xc) * CC + c];

  {  // scale 2: 32x32 source. src = y/2 - 0.25
    const float ty = y * 0.5f - 0.25f;
    const float tx = xc * 0.5f - 0.25f;
    const int iy = (int)floorf(ty), ix = (int)floorf(tx);
    const float wy = ty - iy, wx = tx - ix;
    const int iy0 = max(iy, 0), iy1 = min(iy + 1, 31);
    const int ix0 = max(ix, 0), ix1 = min(ix + 1, 31);
    const float* base = a2 + (size_t)b * 1024 * 64 + c;
    const float v00 = base[(iy0*32+ix0)*64], v01 = base[(iy0*32+ix1)*64];
    const float v10 = base[(iy1*32+ix0)*64], v11 = base[(iy1*32+ix1)*64];
    r += (1.f-wy)*((1.f-wx)*v00 + wx*v01) + wy*((1.f-wx)*v10 + wx*v11);
  }
  {  // scale 4: 16x16 source. src = y/4 - 0.375
    const float ty = y * 0.25f - 0.375f;
    const float tx = xc * 0.25f - 0.375f;
    const int iy = (int)floorf(ty), ix = (int)floorf(tx);
    const float wy = ty - iy, wx = tx - ix;
    const int iy0 = max(iy, 0), iy1 = min(iy + 1, 15);
    const int ix0 = max(ix, 0), ix1 = min(ix + 1, 15);
    const float* base = a4 + (size_t)b * 256 * 64 + c;
    const float v00 = base[(iy0*16+ix0)*64], v01 = base[(iy0*16+ix1)*64];
    const float v10 = base[(iy1*16+ix0)*64], v11 = base[(iy1*16+ix1)*64];
    r += (1.f-wy)*((1.f-wx)*v00 + wx*v01) + wy*((1.f-wx)*v10 + wx*v11);
  }
  out[(((size_t)b * CC + c) * HH + y) * WW + xc] = r;
}

// ---------------------------------------------------------------------------
extern "C" void kernel_launch(void* const* d_in, const int* in_sizes, int n_in,
                              void* d_out, int out_size, void* d_ws,
                              size_t ws_size, hipStream_t stream) {
  const float* x = (const float*)d_in[0];
  const float* w = (const float*)d_in[1];
  float* out = (float*)d_out;

  float* featT = (float*)d_ws;                  // 8*4096*64
  float* p2    = featT + (size_t)BB*NPIX*CC;    // 8*1024*64
  float* p4    = p2    + (size_t)BB*1024*CC;    // 8*256*64
  float* a1    = p4    + (size_t)BB*256*CC;     // 8*4096*64
  float* a2    = a1    + (size_t)BB*NPIX*CC;    // 8*1024*64
  float* a4    = a2    + (size_t)BB*1024*CC;    // 8*256*64

  conv_kernel<<<dim3(16, 64, 8), 256, 0, stream>>>(x, w, featT);
  pool2_kernel<<<(BB*1024*CC)/256, 256, 0, stream>>>(featT, p2, 32);
  pool2_kernel<<<(BB*256*CC)/256, 256, 0, stream>>>(p2, p4, 16);
  attn_kernel<<<dim3(NPIX/64, BB), 256, 0, stream>>>(featT, a1, NPIX);
  attn_kernel<<<dim3(1024/64, BB), 256, 0, stream>>>(p2, a2, 1024);
  attn_kernel<<<dim3(256/64, BB), 256, 0, stream>>>(p4, a4, 256);
  final_kernel<<<dim3(16, 64, 8), 256, 0, stream>>>(x, a1, a2, a4, out);
}

// Round 3
// 804.710 us; speedup vs baseline: 3.7813x; 1.6670x over previous
//
#include <hip/hip_runtime.h>
#include <hip/hip_bf16.h>
#include <math.h>

// Problem constants: x [8,64,64,64] fp32 NCHW, W_std [64,64,3,3] fp32 OIHW.
#define BB 8
#define CC 64
#define HH 64
#define WW 64
#define NPIX (HH*WW)   // 4096

typedef __attribute__((ext_vector_type(8))) short bf16x8;   // MFMA A/B frag (4 VGPR)
typedef __attribute__((ext_vector_type(4))) float floatx4;  // MFMA C/D frag

__device__ inline unsigned short f2bf(float x) {
  __hip_bfloat16 h = __float2bfloat16(x);
  return *reinterpret_cast<unsigned short*>(&h);
}
__device__ inline float bf2f(unsigned short u) {
  __hip_bfloat16 h = *reinterpret_cast<__hip_bfloat16*>(&u);
  return __bfloat162float(h);
}

// ---------------------------------------------------------------------------
// Conv: feat = conv3x3(x, W_std) + depthwise Laplacian(x).
// Emits THREE bf16 views of feat for the MFMA attention:
//   fh [b][n][c] hi bf16, fl [b][n][c] lo bf16 (f ~= fh+fl, ~16-bit mantissa)
//   fv [b][c][n] hi bf16 (channel-major, V operand B-frags)
// ---------------------------------------------------------------------------
__global__ __launch_bounds__(256) void conv_kernel(
    const float* __restrict__ xin, const float* __restrict__ w,
    unsigned short* __restrict__ fh, unsigned short* __restrict__ fl,
    unsigned short* __restrict__ fv) {
  const int xc = threadIdx.x & 63;
  const int yl = threadIdx.x >> 6;
  const int o  = blockIdx.y;
  const int b  = blockIdx.z;
  const int y  = blockIdx.x * 4 + yl;

  const float* xb = xin + (size_t)b * CC * NPIX;
  const float* wo = w + o * (CC * 9);

  float acc = 0.f;
  for (int c = 0; c < CC; ++c) {
    const float* wc = wo + c * 9;
    const float w0 = wc[0], w1 = wc[1], w2 = wc[2];
    const float w3 = wc[3], w4 = wc[4], w5 = wc[5];
    const float w6 = wc[6], w7 = wc[7], w8 = wc[8];
    const float* xcn = xb + c * NPIX;
    float v[3][3];
#pragma unroll
    for (int ky = 0; ky < 3; ++ky) {
      const int yy = y + ky - 1;
      const bool yok = (yy >= 0) && (yy < HH);
      const float* row = xcn + yy * WW;
#pragma unroll
      for (int kx = 0; kx < 3; ++kx) {
        const int xx = xc + kx - 1;
        const bool ok = yok && (xx >= 0) && (xx < WW);
        v[ky][kx] = ok ? row[xx] : 0.f;
      }
    }
    acc += w0*v[0][0] + w1*v[0][1] + w2*v[0][2]
         + w3*v[1][0] + w4*v[1][1] + w5*v[1][2]
         + w6*v[2][0] + w7*v[2][1] + w8*v[2][2];
    if (c == o) {
      acc += v[0][1] + v[2][1] + v[1][0] + v[1][2] - 4.f*v[1][1];
    }
  }
  const int n = y * WW + xc;
  const unsigned short hi = f2bf(acc);
  const unsigned short lo = f2bf(acc - bf2f(hi));
  fh[((size_t)b * NPIX + n) * CC + o] = hi;
  fl[((size_t)b * NPIX + n) * CC + o] = lo;
  fv[((size_t)b * CC + o) * NPIX + n] = hi;
}

// ---------------------------------------------------------------------------
// 2x2 average pool; reads hi+lo (reconstructs fp32 to ~2^-17), writes pooled
// hi/lo/chan-major views. pool4 = pool2(pool2(.)) - numerically equivalent.
// ---------------------------------------------------------------------------
__global__ void pool2_kernel(const unsigned short* __restrict__ in_h,
                             const unsigned short* __restrict__ in_l,
                             unsigned short* __restrict__ out_h,
                             unsigned short* __restrict__ out_l,
                             unsigned short* __restrict__ out_v, int hw_out) {
  const int idx = blockIdx.x * blockDim.x + threadIdx.x;
  const int c  = idx & 63;
  const int t  = idx >> 6;
  const int xo = t % hw_out;
  const int r  = t / hw_out;
  const int yo = r % hw_out;
  const int b  = r / hw_out;
  const int win = 2 * hw_out;
  const size_t base = ((size_t)b * win * win) * CC;
  float s = 0.f;
#pragma unroll
  for (int dy = 0; dy < 2; ++dy)
#pragma unroll
    for (int dx = 0; dx < 2; ++dx) {
      const size_t a = base + ((size_t)(2*yo+dy) * win + (2*xo+dx)) * CC + c;
      s += bf2f(in_h[a]) + bf2f(in_l[a]);
    }
  const float v = 0.25f * s;
  const unsigned short hi = f2bf(v);
  const unsigned short lo = f2bf(v - bf2f(hi));
  const int n = yo * hw_out + xo;
  out_h[idx] = hi;   // idx == ((b*hw^2)+n)*64+c by construction
  out_l[idx] = lo;
  out_v[((size_t)b * CC + c) * (hw_out * hw_out) + n] = hi;
}

// ---------------------------------------------------------------------------
// MFMA flash attention. Block = 4 waves; wave owns 16 Q-rows (q0..q0+15),
// iterates K-tiles of 64 keys with online softmax.
//   S (hi/lo 3-pass, fp32 acc):  6 MFMA per 16x16 S-tile, 4 tiles/K-tile
//   P: D-layout -> LDS (bf16, row stride 72 elems = 144B) -> A-layout frags
//   O += P*V: V B-frags from channel-major fv, 8 MFMA per K-tile
// Row state (m,l) lives per-reg (row = quad*4+reg), replicated across the 16
// lanes of a quad; row reductions are 4x shfl_xor width-16.
// ---------------------------------------------------------------------------
#define STR 72   // P-tile LDS row stride (bf16 elems); 144B keeps b128 aligned

__global__ __launch_bounds__(256, 2) void attn_mfma(
    const unsigned short* __restrict__ fh,
    const unsigned short* __restrict__ fl,
    const unsigned short* __restrict__ fv,
    float* __restrict__ outT, int N) {
  __shared__ __align__(16) unsigned short Pt[4][16 * STR];

  const int lane = threadIdx.x & 63;
  const int wave = threadIdx.x >> 6;
  const int b    = blockIdx.y;
  const int q0   = blockIdx.x * 64 + wave * 16;
  const int r16  = lane & 15;
  const int quad = lane >> 4;

  const unsigned short* fhB = fh + (size_t)b * N * CC;
  const unsigned short* flB = fl + (size_t)b * N * CC;
  const unsigned short* fvB = fv + (size_t)b * CC * N;

  // Q fragments (A-layout): lane holds f[q0+r16][quad*8 .. +8) per k-step
  bf16x8 Qh[2], Ql[2];
#pragma unroll
  for (int ks = 0; ks < 2; ++ks) {
    const size_t off = (size_t)(q0 + r16) * CC + ks * 32 + quad * 8;
    Qh[ks] = *(const bf16x8*)(fhB + off);
    Ql[ks] = *(const bf16x8*)(flB + off);
  }

  floatx4 O[4];
#pragma unroll
  for (int ch = 0; ch < 4; ++ch) O[ch] = (floatx4){0.f, 0.f, 0.f, 0.f};
  float mrun[4] = {-INFINITY, -INFINITY, -INFINITY, -INFINITY};
  float lrun[4] = {0.f, 0.f, 0.f, 0.f};

  unsigned short* pt = Pt[wave];

  for (int m0 = 0; m0 < N; m0 += 64) {
    // ---- S-tiles: S[q][m], 4 m-tiles of 16 ----
    floatx4 S[4];
#pragma unroll
    for (int t = 0; t < 4; ++t) {
      const size_t kb = (size_t)(m0 + t * 16 + r16) * CC + quad * 8;
      const bf16x8 Kh0 = *(const bf16x8*)(fhB + kb);
      const bf16x8 Kh1 = *(const bf16x8*)(fhB + kb + 32);
      const bf16x8 Kl0 = *(const bf16x8*)(flB + kb);
      const bf16x8 Kl1 = *(const bf16x8*)(flB + kb + 32);
      floatx4 s = (floatx4){0.f, 0.f, 0.f, 0.f};
      s = __builtin_amdgcn_mfma_f32_16x16x32_bf16(Qh[0], Kh0, s, 0, 0, 0);
      s = __builtin_amdgcn_mfma_f32_16x16x32_bf16(Qh[1], Kh1, s, 0, 0, 0);
      s = __builtin_amdgcn_mfma_f32_16x16x32_bf16(Ql[0], Kh0, s, 0, 0, 0);
      s = __builtin_amdgcn_mfma_f32_16x16x32_bf16(Ql[1], Kh1, s, 0, 0, 0);
      s = __builtin_amdgcn_mfma_f32_16x16x32_bf16(Qh[0], Kl0, s, 0, 0, 0);
      s = __builtin_amdgcn_mfma_f32_16x16x32_bf16(Qh[1], Kl1, s, 0, 0, 0);
      S[t] = s;
    }

    // ---- online softmax (rows = quad*4 + r, cols spread over quad lanes) --
    float al[4];
#pragma unroll
    for (int r = 0; r < 4; ++r) {
      float mx = fmaxf(fmaxf(S[0][r], S[1][r]), fmaxf(S[2][r], S[3][r]));
      mx = fmaxf(mx, __shfl_xor(mx, 1, 16));
      mx = fmaxf(mx, __shfl_xor(mx, 2, 16));
      mx = fmaxf(mx, __shfl_xor(mx, 4, 16));
      mx = fmaxf(mx, __shfl_xor(mx, 8, 16));
      const float mnew = fmaxf(mrun[r], mx);
      al[r] = __expf(mrun[r] - mnew);   // first tile: exp(-inf)=0
      mrun[r] = mnew;
      float ls = 0.f;
#pragma unroll
      for (int t = 0; t < 4; ++t) {
        const float p = __expf(S[t][r] - mnew);   // always <= 0 in exponent
        S[t][r] = p;
        ls += p;
      }
      ls += __shfl_xor(ls, 1, 16);
      ls += __shfl_xor(ls, 2, 16);
      ls += __shfl_xor(ls, 4, 16);
      ls += __shfl_xor(ls, 8, 16);
      lrun[r] = lrun[r] * al[r] + ls;
    }
#pragma unroll
    for (int ch = 0; ch < 4; ++ch)
#pragma unroll
      for (int r = 0; r < 4; ++r) O[ch][r] *= al[r];

    // ---- P: D-layout -> LDS ----
#pragma unroll
    for (int t = 0; t < 4; ++t)
#pragma unroll
      for (int r = 0; r < 4; ++r)
        pt[(quad * 4 + r) * STR + t * 16 + r16] = f2bf(S[t][r]);

    // ---- O += P*V ----
#pragma unroll
    for (int ks = 0; ks < 2; ++ks) {
      const bf16x8 Pf = *(const bf16x8*)(pt + r16 * STR + ks * 32 + quad * 8);
#pragma unroll
      for (int ch = 0; ch < 4; ++ch) {
        const size_t vb = (size_t)(ch * 16 + r16) * N + m0 + ks * 32 + quad * 8;
        const bf16x8 Vf = *(const bf16x8*)(fvB + vb);
        O[ch] = __builtin_amdgcn_mfma_f32_16x16x32_bf16(Pf, Vf, O[ch], 0, 0, 0);
      }
    }
  }

  // ---- epilogue: normalize, store [b][q][c] fp32 ----
#pragma unroll
  for (int ch = 0; ch < 4; ++ch)
#pragma unroll
    for (int r = 0; r < 4; ++r)
      outT[((size_t)b * N + q0 + quad * 4 + r) * CC + ch * 16 + r16] =
          O[ch][r] / lrun[r];
}

// ---------------------------------------------------------------------------
// out[b][c][y][x] = x + a1[b][n][c] + bilinear_up2(a2) + bilinear_up4(a4)
// ---------------------------------------------------------------------------
__global__ __launch_bounds__(256) void final_kernel(
    const float* __restrict__ xin, const float* __restrict__ a1,
    const float* __restrict__ a2, const float* __restrict__ a4,
    float* __restrict__ out) {
  const int xc = threadIdx.x & 63;
  const int yl = threadIdx.x >> 6;
  const int y  = blockIdx.x * 4 + yl;
  const int c  = blockIdx.y;
  const int b  = blockIdx.z;

  float r = xin[(((size_t)b * CC + c) * HH + y) * WW + xc];
  r += a1[((size_t)b * NPIX + y * WW + xc) * CC + c];

  {  // scale 2: 32x32 source. src = y/2 - 0.25
    const float ty = y * 0.5f - 0.25f;
    const float tx = xc * 0.5f - 0.25f;
    const int iy = (int)floorf(ty), ix = (int)floorf(tx);
    const float wy = ty - iy, wx = tx - ix;
    const int iy0 = max(iy, 0), iy1 = min(iy + 1, 31);
    const int ix0 = max(ix, 0), ix1 = min(ix + 1, 31);
    const float* base = a2 + (size_t)b * 1024 * 64 + c;
    const float v00 = base[(iy0*32+ix0)*64], v01 = base[(iy0*32+ix1)*64];
    const float v10 = base[(iy1*32+ix0)*64], v11 = base[(iy1*32+ix1)*64];
    r += (1.f-wy)*((1.f-wx)*v00 + wx*v01) + wy*((1.f-wx)*v10 + wx*v11);
  }
  {  // scale 4: 16x16 source. src = y/4 - 0.375
    const float ty = y * 0.25f - 0.375f;
    const float tx = xc * 0.25f - 0.375f;
    const int iy = (int)floorf(ty), ix = (int)floorf(tx);
    const float wy = ty - iy, wx = tx - ix;
    const int iy0 = max(iy, 0), iy1 = min(iy + 1, 15);
    const int ix0 = max(ix, 0), ix1 = min(ix + 1, 15);
    const float* base = a4 + (size_t)b * 256 * 64 + c;
    const float v00 = base[(iy0*16+ix0)*64], v01 = base[(iy0*16+ix1)*64];
    const float v10 = base[(iy1*16+ix0)*64], v11 = base[(iy1*16+ix1)*64];
    r += (1.f-wy)*((1.f-wx)*v00 + wx*v01) + wy*((1.f-wx)*v10 + wx*v11);
  }
  out[(((size_t)b * CC + c) * HH + y) * WW + xc] = r;
}

// ---------------------------------------------------------------------------
extern "C" void kernel_launch(void* const* d_in, const int* in_sizes, int n_in,
                              void* d_out, int out_size, void* d_ws,
                              size_t ws_size, hipStream_t stream) {
  const float* x = (const float*)d_in[0];
  const float* w = (const float*)d_in[1];
  float* out = (float*)d_out;

  // Workspace layout (27.5 MB total)
  unsigned short* fh1 = (unsigned short*)d_ws;            // [8][4096][64]
  unsigned short* fl1 = fh1 + (size_t)BB*NPIX*CC;
  unsigned short* fv1 = fl1 + (size_t)BB*NPIX*CC;         // [8][64][4096]
  unsigned short* fh2 = fv1 + (size_t)BB*NPIX*CC;         // [8][1024][64]
  unsigned short* fl2 = fh2 + (size_t)BB*1024*CC;
  unsigned short* fv2 = fl2 + (size_t)BB*1024*CC;
  unsigned short* fh4 = fv2 + (size_t)BB*1024*CC;         // [8][256][64]
  unsigned short* fl4 = fh4 + (size_t)BB*256*CC;
  unsigned short* fv4 = fl4 + (size_t)BB*256*CC;
  float* a1 = (float*)(fv4 + (size_t)BB*256*CC);          // fp32 outputs
  float* a2 = a1 + (size_t)BB*NPIX*CC;
  float* a4 = a2 + (size_t)BB*1024*CC;

  conv_kernel<<<dim3(16, 64, 8), 256, 0, stream>>>(x, w, fh1, fl1, fv1);
  pool2_kernel<<<(BB*1024*CC)/256, 256, 0, stream>>>(fh1, fl1, fh2, fl2, fv2, 32);
  pool2_kernel<<<(BB*256*CC)/256, 256, 0, stream>>>(fh2, fl2, fh4, fl4, fv4, 16);
  attn_mfma<<<dim3(NPIX/64, BB), 256, 0, stream>>>(fh1, fl1, fv1, a1, NPIX);
  attn_mfma<<<dim3(1024/64, BB), 256, 0, stream>>>(fh2, fl2, fv2, a2, 1024);
  attn_mfma<<<dim3(256/64, BB), 256, 0, stream>>>(fh4, fl4, fv4, a4, 256);
  final_kernel<<<dim3(16, 64, 8), 256, 0, stream>>>(x, a1, a2, a4, out);
}

// Round 4
// 385.116 us; speedup vs baseline: 7.9012x; 2.0895x over previous
//
#include <hip/hip_runtime.h>
#include <hip/hip_bf16.h>
#include <math.h>

// Problem constants: x [8,64,64,64] fp32 NCHW, W_std [64,64,3,3] fp32 OIHW.
#define BB 8
#define CC 64
#define HH 64
#define WW 64
#define NPIX (HH*WW)   // 4096

typedef __attribute__((ext_vector_type(8))) short bf16x8;            // MFMA A/B frag
typedef __attribute__((ext_vector_type(4))) float floatx4;           // MFMA C/D frag
typedef __attribute__((ext_vector_type(8))) unsigned short ushort8;  // 16B staging unit

__device__ inline unsigned short f2bf(float x) {
  __hip_bfloat16 h = __float2bfloat16(x);
  return *reinterpret_cast<unsigned short*>(&h);
}
__device__ inline float bf2f(unsigned short u) {
  __hip_bfloat16 h = *reinterpret_cast<__hip_bfloat16*>(&u);
  return __bfloat162float(h);
}

// XOR swizzle: 16B channel-chunks permuted within each 128B row so that MFMA
// fragment reads from LDS (lane stride 128B) spread across all 32 banks.
// fh/fl element (b,n,c) -> [(b*N+n)*64 + swzoff(n,c)]
__device__ inline int swzoff(int n, int c) {
  return (((c >> 3) ^ (n & 7)) << 3) | (c & 7);
}
// fv (tile-major V^T): n = t*64+key -> [((b*(N/64)+t)*64 + c)*64 + swzvslot(key,c)]
__device__ inline int swzvslot(int key, int c) {
  return (((key >> 3) ^ (c & 7)) << 3) | (key & 7);
}

// ---------------------------------------------------------------------------
// Conv: feat = conv3x3(x, W_std) + depthwise Laplacian(x).
// 4 y-outputs per thread (rows y0-1..y0+4 loaded once per c: 18 loads for 4
// outputs vs 9/output before). Emits swizzled fh/fl [n][c] and tile-major
// swizzled fv. grid (4 ytiles16, 64 o, 8 b), block 256 = 64x * 4yt.
// ---------------------------------------------------------------------------
__global__ __launch_bounds__(256) void conv_kernel(
    const float* __restrict__ xin, const float* __restrict__ w,
    unsigned short* __restrict__ fh, unsigned short* __restrict__ fl,
    unsigned short* __restrict__ fv) {
  const int xc = threadIdx.x & 63;
  const int yt = threadIdx.x >> 6;
  const int o  = blockIdx.y;
  const int b  = blockIdx.z;
  const int y0 = blockIdx.x * 16 + yt * 4;

  const float* xb = xin + (size_t)b * CC * NPIX;
  const float* wo = w + o * (CC * 9);

  float acc[4] = {0.f, 0.f, 0.f, 0.f};
  for (int c = 0; c < CC; ++c) {
    const float* wc = wo + c * 9;
    float W[9];
#pragma unroll
    for (int k = 0; k < 9; ++k) W[k] = wc[k];   // wave-uniform -> s_load
    const float* xcn = xb + c * NPIX;
    float v[6][3];
#pragma unroll
    for (int rr = 0; rr < 6; ++rr) {
      const int yy = y0 - 1 + rr;
      const bool yok = (yy >= 0) && (yy < HH);
      const float* row = xcn + yy * WW;
#pragma unroll
      for (int kx = 0; kx < 3; ++kx) {
        const int xx = xc + kx - 1;
        const bool ok = yok && (xx >= 0) && (xx < WW);
        v[rr][kx] = ok ? row[xx] : 0.f;
      }
    }
#pragma unroll
    for (int i = 0; i < 4; ++i) {
      acc[i] += W[0]*v[i][0]   + W[1]*v[i][1]   + W[2]*v[i][2]
              + W[3]*v[i+1][0] + W[4]*v[i+1][1] + W[5]*v[i+1][2]
              + W[6]*v[i+2][0] + W[7]*v[i+2][1] + W[8]*v[i+2][2];
    }
    if (c == o) {  // fixed depthwise Laplacian on matching channel
#pragma unroll
      for (int i = 0; i < 4; ++i)
        acc[i] += v[i][1] + v[i+2][1] + v[i+1][0] + v[i+1][2] - 4.f*v[i+1][1];
    }
  }
#pragma unroll
  for (int i = 0; i < 4; ++i) {
    const int y = y0 + i;
    const int n = y * WW + xc;                 // n&7 == xc&7
    const unsigned short hi = f2bf(acc[i]);
    const unsigned short lo = f2bf(acc[i] - bf2f(hi));
    fh[((size_t)b * NPIX + n) * CC + swzoff(n, o)] = hi;
    fl[((size_t)b * NPIX + n) * CC + swzoff(n, o)] = lo;
    // tile index = n>>6 = y, key = n&63 = xc
    fv[(((size_t)b * (NPIX >> 6) + y) * CC + o) * 64 + swzvslot(xc, o)] = hi;
  }
}

// ---------------------------------------------------------------------------
// 2x2 average pool on swizzled layout; reconstructs fp32 from hi+lo, writes
// pooled swizzled hi/lo + tile-major swizzled V view.
// ---------------------------------------------------------------------------
__global__ void pool2_kernel(const unsigned short* __restrict__ in_h,
                             const unsigned short* __restrict__ in_l,
                             unsigned short* __restrict__ out_h,
                             unsigned short* __restrict__ out_l,
                             unsigned short* __restrict__ out_v, int hw_out) {
  const int idx = blockIdx.x * blockDim.x + threadIdx.x;
  const int c  = idx & 63;
  const int t  = idx >> 6;
  const int xo = t % hw_out;
  const int r  = t / hw_out;
  const int yo = r % hw_out;
  const int b  = r / hw_out;
  const int win = 2 * hw_out;
  const size_t ibase = (size_t)b * win * win * CC;
  float s = 0.f;
#pragma unroll
  for (int dy = 0; dy < 2; ++dy)
#pragma unroll
    for (int dx = 0; dx < 2; ++dx) {
      const int nin = (2*yo+dy) * win + (2*xo+dx);
      const size_t a = ibase + (size_t)nin * CC + swzoff(nin, c);
      s += bf2f(in_h[a]) + bf2f(in_l[a]);
    }
  const float vv = 0.25f * s;
  const unsigned short hi = f2bf(vv);
  const unsigned short lo = f2bf(vv - bf2f(hi));
  const int nout = yo * hw_out + xo;
  const int Nout = hw_out * hw_out;
  const size_t ob = ((size_t)b * Nout + nout) * CC + swzoff(nout, c);
  out_h[ob] = hi;
  out_l[ob] = lo;
  out_v[(((size_t)b * (Nout >> 6) + (nout >> 6)) * CC + c) * 64
        + swzvslot(nout & 63, c)] = hi;
}

// ---------------------------------------------------------------------------
// MFMA flash attention with cooperative LDS staging + ping-pong prefetch.
// Block = 4 waves x 16 Q-rows = 64 Q. Per 64-key tile the block stages
// Kh/Kl/V^T (3x8KB, contiguous copies; swizzle already in global layout) into
// LDS, shared by all 4 waves. Tile t+1 is register-prefetched right after the
// barrier and ds_written at the end of compute (latency hidden by ~1000cyc of
// MFMA+softmax). One barrier/tile; write buffer != read buffer.
// ---------------------------------------------------------------------------
#define STR 72   // P-tile LDS row stride (shorts); 144B keeps b128 aligned

__global__ __launch_bounds__(256, 2) void attn_mfma(
    const unsigned short* __restrict__ fh,
    const unsigned short* __restrict__ fl,
    const unsigned short* __restrict__ fv,
    float* __restrict__ outT, int N) {
  __shared__ __align__(16) unsigned short KhT[2][4096];
  __shared__ __align__(16) unsigned short KlT[2][4096];
  __shared__ __align__(16) unsigned short VtT[2][4096];
  __shared__ __align__(16) unsigned short Pt[4][16 * STR];

  const int tid  = threadIdx.x;
  const int lane = tid & 63;
  const int wave = tid >> 6;
  const int b    = blockIdx.y;
  const int q0   = blockIdx.x * 64 + wave * 16;
  const int r16  = lane & 15;
  const int quad = lane >> 4;
  const int swb  = r16 & 7;            // swizzle factor: = key&7 = q&7 = c&7

  const unsigned short* fhB = fh + (size_t)b * N * CC;
  const unsigned short* flB = fl + (size_t)b * N * CC;
  const unsigned short* fvB = fv + (size_t)b * N * CC;   // tile-major V^T

  // Q fragments (A-layout) from swizzled global
  bf16x8 Qh[2], Ql[2];
#pragma unroll
  for (int ks = 0; ks < 2; ++ks) {
    const int q = q0 + r16;
    const size_t off = (size_t)q * CC + ((((ks << 2) + quad) ^ swb) << 3);
    Qh[ks] = *(const bf16x8*)(fhB + off);
    Ql[ks] = *(const bf16x8*)(flB + off);
  }

  // lane-constant fragment chunk offsets (shorts) inside a 64-short row
  int koff[2];
#pragma unroll
  for (int ks = 0; ks < 2; ++ks) koff[ks] = (((ks << 2) + quad) ^ swb) << 3;

  floatx4 O[4];
#pragma unroll
  for (int ch = 0; ch < 4; ++ch) O[ch] = (floatx4){0.f, 0.f, 0.f, 0.f};
  float mrun[4] = {-INFINITY, -INFINITY, -INFINITY, -INFINITY};
  float lrun[4] = {0.f, 0.f, 0.f, 0.f};
  unsigned short* pt = Pt[wave];

  const int nt = N >> 6;
  ushort8 pKh[2], pKl[2], pVt[2];
  // stage tile 0 (load + write; one-time latency)
#pragma unroll
  for (int j = 0; j < 2; ++j) {
    const int u = (tid + j * 256) * 8;
    pKh[j] = *(const ushort8*)(fhB + u);
    pKl[j] = *(const ushort8*)(flB + u);
    pVt[j] = *(const ushort8*)(fvB + u);
  }
#pragma unroll
  for (int j = 0; j < 2; ++j) {
    const int u = (tid + j * 256) * 8;
    *(ushort8*)(&KhT[0][u]) = pKh[j];
    *(ushort8*)(&KlT[0][u]) = pKl[j];
    *(ushort8*)(&VtT[0][u]) = pVt[j];
  }

  for (int t = 0; t < nt; ++t) {
    const int cur = t & 1;
    const bool more = (t + 1 < nt);
    __syncthreads();                        // staging of cur visible to all
    if (more) {                             // issue next-tile loads NOW
      const size_t tb = (size_t)(t + 1) * 4096;
#pragma unroll
      for (int j = 0; j < 2; ++j) {
        const int u = (tid + j * 256) * 8;
        pKh[j] = *(const ushort8*)(fhB + tb + u);
        pKl[j] = *(const ushort8*)(flB + tb + u);
        pVt[j] = *(const ushort8*)(fvB + tb + u);
      }
    }
    const unsigned short* kh = KhT[cur];
    const unsigned short* kl = KlT[cur];
    const unsigned short* vt = VtT[cur];

    // ---- S-tiles: S[q][m] via 6 MFMA (hi/lo 3-pass) per 16-key tile ----
    floatx4 S[4];
#pragma unroll
    for (int tt = 0; tt < 4; ++tt) {
      const int kbase = (tt * 16 + r16) * 64;
      const bf16x8 Kh0 = *(const bf16x8*)(kh + kbase + koff[0]);
      const bf16x8 Kh1 = *(const bf16x8*)(kh + kbase + koff[1]);
      const bf16x8 Kl0 = *(const bf16x8*)(kl + kbase + koff[0]);
      const bf16x8 Kl1 = *(const bf16x8*)(kl + kbase + koff[1]);
      floatx4 s = (floatx4){0.f, 0.f, 0.f, 0.f};
      s = __builtin_amdgcn_mfma_f32_16x16x32_bf16(Qh[0], Kh0, s, 0, 0, 0);
      s = __builtin_amdgcn_mfma_f32_16x16x32_bf16(Qh[1], Kh1, s, 0, 0, 0);
      s = __builtin_amdgcn_mfma_f32_16x16x32_bf16(Ql[0], Kh0, s, 0, 0, 0);
      s = __builtin_amdgcn_mfma_f32_16x16x32_bf16(Ql[1], Kh1, s, 0, 0, 0);
      s = __builtin_amdgcn_mfma_f32_16x16x32_bf16(Qh[0], Kl0, s, 0, 0, 0);
      s = __builtin_amdgcn_mfma_f32_16x16x32_bf16(Qh[1], Kl1, s, 0, 0, 0);
      S[tt] = s;
    }

    // ---- online softmax ----
    float al[4];
#pragma unroll
    for (int r = 0; r < 4; ++r) {
      float mx = fmaxf(fmaxf(S[0][r], S[1][r]), fmaxf(S[2][r], S[3][r]));
      mx = fmaxf(mx, __shfl_xor(mx, 1, 16));
      mx = fmaxf(mx, __shfl_xor(mx, 2, 16));
      mx = fmaxf(mx, __shfl_xor(mx, 4, 16));
      mx = fmaxf(mx, __shfl_xor(mx, 8, 16));
      const float mnew = fmaxf(mrun[r], mx);
      al[r] = __expf(mrun[r] - mnew);       // first tile: exp(-inf)=0
      mrun[r] = mnew;
      float ls = 0.f;
#pragma unroll
      for (int tt = 0; tt < 4; ++tt) {
        const float p = __expf(S[tt][r] - mnew);
        S[tt][r] = p;
        ls += p;
      }
      ls += __shfl_xor(ls, 1, 16);
      ls += __shfl_xor(ls, 2, 16);
      ls += __shfl_xor(ls, 4, 16);
      ls += __shfl_xor(ls, 8, 16);
      lrun[r] = lrun[r] * al[r] + ls;
    }
#pragma unroll
    for (int ch = 0; ch < 4; ++ch)
#pragma unroll
      for (int r = 0; r < 4; ++r) O[ch][r] *= al[r];

    // ---- P: D-layout -> LDS (per-wave private; lgkmcnt only) ----
#pragma unroll
    for (int tt = 0; tt < 4; ++tt)
#pragma unroll
      for (int r = 0; r < 4; ++r)
        pt[(quad * 4 + r) * STR + tt * 16 + r16] = f2bf(S[tt][r]);

    // ---- O += P*V ----
#pragma unroll
    for (int ks = 0; ks < 2; ++ks) {
      const bf16x8 Pf = *(const bf16x8*)(pt + r16 * STR + ks * 32 + quad * 8);
#pragma unroll
      for (int ch = 0; ch < 4; ++ch) {
        const bf16x8 Vf = *(const bf16x8*)(vt + (ch * 16 + r16) * 64 + koff[ks]);
        O[ch] = __builtin_amdgcn_mfma_f32_16x16x32_bf16(Pf, Vf, O[ch], 0, 0, 0);
      }
    }

    // ---- commit prefetched tile t+1 to the other buffer ----
    if (more) {
      const int nb = 1 - cur;
#pragma unroll
      for (int j = 0; j < 2; ++j) {
        const int u = (tid + j * 256) * 8;
        *(ushort8*)(&KhT[nb][u]) = pKh[j];
        *(ushort8*)(&KlT[nb][u]) = pKl[j];
        *(ushort8*)(&VtT[nb][u]) = pVt[j];
      }
    }
  }

  // ---- epilogue: normalize, store [b][q][c] fp32 (non-swizzled) ----
#pragma unroll
  for (int ch = 0; ch < 4; ++ch)
#pragma unroll
    for (int r = 0; r < 4; ++r)
      outT[((size_t)b * N + q0 + quad * 4 + r) * CC + ch * 16 + r16] =
          O[ch][r] / lrun[r];
}

// ---------------------------------------------------------------------------
// out[b][c][y][x] = x + a1[b][n][c] + bilinear_up2(a2) + bilinear_up4(a4)
// ---------------------------------------------------------------------------
__global__ __launch_bounds__(256) void final_kernel(
    const float* __restrict__ xin, const float* __restrict__ a1,
    const float* __restrict__ a2, const float* __restrict__ a4,
    float* __restrict__ out) {
  const int xc = threadIdx.x & 63;
  const int yl = threadIdx.x >> 6;
  const int y  = blockIdx.x * 4 + yl;
  const int c  = blockIdx.y;
  const int b  = blockIdx.z;

  float r = xin[(((size_t)b * CC + c) * HH + y) * WW + xc];
  r += a1[((size_t)b * NPIX + y * WW + xc) * CC + c];

  {  // scale 2: 32x32 source. src = y/2 - 0.25
    const float ty = y * 0.5f - 0.25f;
    const float tx = xc * 0.5f - 0.25f;
    const int iy = (int)floorf(ty), ix = (int)floorf(tx);
    const float wy = ty - iy, wx = tx - ix;
    const int iy0 = max(iy, 0), iy1 = min(iy + 1, 31);
    const int ix0 = max(ix, 0), ix1 = min(ix + 1, 31);
    const float* base = a2 + (size_t)b * 1024 * 64 + c;
    const float v00 = base[(iy0*32+ix0)*64], v01 = base[(iy0*32+ix1)*64];
    const float v10 = base[(iy1*32+ix0)*64], v11 = base[(iy1*32+ix1)*64];
    r += (1.f-wy)*((1.f-wx)*v00 + wx*v01) + wy*((1.f-wx)*v10 + wx*v11);
  }
  {  // scale 4: 16x16 source. src = y/4 - 0.375
    const float ty = y * 0.25f - 0.375f;
    const float tx = xc * 0.25f - 0.375f;
    const int iy = (int)floorf(ty), ix = (int)floorf(tx);
    const float wy = ty - iy, wx = tx - ix;
    const int iy0 = max(iy, 0), iy1 = min(iy + 1, 15);
    const int ix0 = max(ix, 0), ix1 = min(ix + 1, 15);
    const float* base = a4 + (size_t)b * 256 * 64 + c;
    const float v00 = base[(iy0*16+ix0)*64], v01 = base[(iy0*16+ix1)*64];
    const float v10 = base[(iy1*16+ix0)*64], v11 = base[(iy1*16+ix1)*64];
    r += (1.f-wy)*((1.f-wx)*v00 + wx*v01) + wy*((1.f-wx)*v10 + wx*v11);
  }
  out[(((size_t)b * CC + c) * HH + y) * WW + xc] = r;
}

// ---------------------------------------------------------------------------
extern "C" void kernel_launch(void* const* d_in, const int* in_sizes, int n_in,
                              void* d_out, int out_size, void* d_ws,
                              size_t ws_size, hipStream_t stream) {
  const float* x = (const float*)d_in[0];
  const float* w = (const float*)d_in[1];
  float* out = (float*)d_out;

  unsigned short* fh1 = (unsigned short*)d_ws;            // [8][4096][64] swz
  unsigned short* fl1 = fh1 + (size_t)BB*NPIX*CC;
  unsigned short* fv1 = fl1 + (size_t)BB*NPIX*CC;         // tile-major V^T
  unsigned short* fh2 = fv1 + (size_t)BB*NPIX*CC;         // [8][1024][64]
  unsigned short* fl2 = fh2 + (size_t)BB*1024*CC;
  unsigned short* fv2 = fl2 + (size_t)BB*1024*CC;
  unsigned short* fh4 = fv2 + (size_t)BB*1024*CC;         // [8][256][64]
  unsigned short* fl4 = fh4 + (size_t)BB*256*CC;
  unsigned short* fv4 = fl4 + (size_t)BB*256*CC;
  float* a1 = (float*)(fv4 + (size_t)BB*256*CC);          // fp32 outputs
  float* a2 = a1 + (size_t)BB*NPIX*CC;
  float* a4 = a2 + (size_t)BB*1024*CC;

  conv_kernel<<<dim3(4, 64, 8), 256, 0, stream>>>(x, w, fh1, fl1, fv1);
  pool2_kernel<<<(BB*1024*CC)/256, 256, 0, stream>>>(fh1, fl1, fh2, fl2, fv2, 32);
  pool2_kernel<<<(BB*256*CC)/256, 256, 0, stream>>>(fh2, fl2, fh4, fl4, fv4, 16);
  attn_mfma<<<dim3(NPIX/64, BB), 256, 0, stream>>>(fh1, fl1, fv1, a1, NPIX);
  attn_mfma<<<dim3(1024/64, BB), 256, 0, stream>>>(fh2, fl2, fv2, a2, 1024);
  attn_mfma<<<dim3(256/64, BB), 256, 0, stream>>>(fh4, fl4, fv4, a4, 256);
  final_kernel<<<dim3(16, 64, 8), 256, 0, stream>>>(x, a1, a2, a4, out);
}